// Round 2
// baseline (504.622 us; speedup 1.0000x reference)
//
#include <hip/hip_runtime.h>
#include <cstdint>
#include <cstddef>

typedef short short8 __attribute__((ext_vector_type(8)));
typedef float floatx4 __attribute__((ext_vector_type(4)));
typedef unsigned short ushort4v __attribute__((ext_vector_type(4)));
typedef unsigned short ushort2v __attribute__((ext_vector_type(2)));

#define AS1C(p) ((const __attribute__((address_space(1))) void*)(p))
#define AS3(p)  ((__attribute__((address_space(3))) void*)(p))

// round-to-nearest-even float -> bf16 bits
__device__ __forceinline__ unsigned short f2bf(float f) {
    union { float f; unsigned int u; } v; v.f = f;
    unsigned int u = v.u;
    unsigned int r = (u + 0x7fffu + ((u >> 16) & 1u)) >> 16;
    return (unsigned short)r;
}

__device__ __forceinline__ float wave_sum(float s) {
#pragma unroll
    for (int off = 32; off > 0; off >>= 1)
        s += __shfl_xor(s, off, 64);
    return s;
}

// ---------------------------------------------------------------------------
// Kernel 1: per-row l2norm of feats -> fb (bf16); store rnorm[i]; histogram
// labels with ONE int atomic per row. One wave per row of D=512.
// ---------------------------------------------------------------------------
__global__ __launch_bounds__(256) void k_norm(
    const float* __restrict__ feats, const int* __restrict__ labels,
    unsigned short* __restrict__ fb, float* __restrict__ rnorm,
    int* __restrict__ cnt, int N)
{
    const int gw   = (int)((blockIdx.x * 256u + threadIdx.x) >> 6);
    const int lane = threadIdx.x & 63;
    if (gw >= N) return;

    const float* row = feats + (size_t)gw * 512;
    floatx4 x0 = *(const floatx4*)(row + lane * 4);
    floatx4 x1 = *(const floatx4*)(row + 256 + lane * 4);

    float s = x0.x * x0.x + x0.y * x0.y + x0.z * x0.z + x0.w * x0.w
            + x1.x * x1.x + x1.y * x1.y + x1.z * x1.z + x1.w * x1.w;
    s = wave_sum(s);
    const float inv = 1.0f / fmaxf(sqrtf(s), 1e-12f);

    floatx4 y0 = x0 * inv, y1 = x1 * inv;

    ushort4v b0, b1;
    b0.x = f2bf(y0.x); b0.y = f2bf(y0.y); b0.z = f2bf(y0.z); b0.w = f2bf(y0.w);
    b1.x = f2bf(y1.x); b1.y = f2bf(y1.y); b1.z = f2bf(y1.z); b1.w = f2bf(y1.w);
    *(ushort4v*)(fb + (size_t)gw * 512 + lane * 4)       = b0;
    *(ushort4v*)(fb + (size_t)gw * 512 + 256 + lane * 4) = b1;

    if (lane == 0) {
        rnorm[gw] = inv;
        atomicAdd(cnt + labels[gw], 1);
    }
}

// ---------------------------------------------------------------------------
// Kernel 2: exclusive prefix-sum of cnt[C] -> offs[C]; cursor = offs.
// ---------------------------------------------------------------------------
__global__ __launch_bounds__(256) void k_scan(
    const int* __restrict__ cnt, int* __restrict__ offs,
    int* __restrict__ cursor, int C)
{
    __shared__ int part[256];
    const int t = threadIdx.x;
    const int base = t * 4;
    int a0 = (base + 0 < C) ? cnt[base + 0] : 0;
    int a1 = (base + 1 < C) ? cnt[base + 1] : 0;
    int a2 = (base + 2 < C) ? cnt[base + 2] : 0;
    int a3 = (base + 3 < C) ? cnt[base + 3] : 0;
    const int s = a0 + a1 + a2 + a3;
    part[t] = s;
    __syncthreads();
#pragma unroll
    for (int off = 1; off < 256; off <<= 1) {
        int v = (t >= off) ? part[t - off] : 0;
        __syncthreads();
        part[t] += v;
        __syncthreads();
    }
    const int excl = part[t] - s;
    const int o0 = excl, o1 = o0 + a0, o2 = o1 + a1, o3 = o2 + a2;
    if (base + 0 < C) { offs[base + 0] = o0; cursor[base + 0] = o0; }
    if (base + 1 < C) { offs[base + 1] = o1; cursor[base + 1] = o1; }
    if (base + 2 < C) { offs[base + 2] = o2; cursor[base + 2] = o2; }
    if (base + 3 < C) { offs[base + 3] = o3; cursor[base + 3] = o3; }
}

// ---------------------------------------------------------------------------
// Kernel 3: build per-class row-index lists.
// ---------------------------------------------------------------------------
__global__ __launch_bounds__(256) void k_scatter_idx(
    const int* __restrict__ labels, int* __restrict__ cursor,
    int* __restrict__ idx, int N)
{
    const int i = (int)(blockIdx.x * 256u + threadIdx.x);
    if (i < N) {
        const int lab = labels[i];
        const int pos = atomicAdd(cursor + lab, 1);
        idx[pos] = i;
    }
}

// ---------------------------------------------------------------------------
// Kernel 4: per-class gather segment-sum + EMA + renorm; write pb (bf16).
// ---------------------------------------------------------------------------
__global__ __launch_bounds__(256) void k_segsum_update(
    const float* __restrict__ feats, const float* __restrict__ rnorm,
    const int* __restrict__ idx, const int* __restrict__ offs,
    const int* __restrict__ cnt, const float* __restrict__ protos,
    unsigned short* __restrict__ pb)
{
    const int c = blockIdx.x;
    const int t = threadIdx.x;
    const int n = cnt[c];
    const int o = offs[c];

    float a0 = 0.0f, a1 = 0.0f;
    int j = 0;
    for (; j + 4 <= n; j += 4) {
        const int r0 = idx[o + j + 0];
        const int r1 = idx[o + j + 1];
        const int r2 = idx[o + j + 2];
        const int r3 = idx[o + j + 3];
        const float2 v0 = *(const float2*)(feats + (size_t)r0 * 512 + t * 2);
        const float2 v1 = *(const float2*)(feats + (size_t)r1 * 512 + t * 2);
        const float2 v2 = *(const float2*)(feats + (size_t)r2 * 512 + t * 2);
        const float2 v3 = *(const float2*)(feats + (size_t)r3 * 512 + t * 2);
        const float s0 = rnorm[r0], s1 = rnorm[r1], s2 = rnorm[r2], s3 = rnorm[r3];
        a0 += v0.x * s0 + v1.x * s1 + v2.x * s2 + v3.x * s3;
        a1 += v0.y * s0 + v1.y * s1 + v2.y * s2 + v3.y * s3;
    }
    for (; j < n; ++j) {
        const int r = idx[o + j];
        const float2 v = *(const float2*)(feats + (size_t)r * 512 + t * 2);
        const float sc = rnorm[r];
        a0 += v.x * sc;
        a1 += v.y * sc;
    }

    const float2 p = *(const float2*)(protos + (size_t)c * 512 + t * 2);
    const float rc = 0.1f / fmaxf((float)n, 1.0f);
    const float v0 = 0.9f * p.x + rc * a0;
    const float v1 = 0.9f * p.y + rc * a1;

    __shared__ float red[256];
    red[t] = v0 * v0 + v1 * v1;
    __syncthreads();
#pragma unroll
    for (int off = 128; off > 0; off >>= 1) {
        if (t < off) red[t] += red[t + off];
        __syncthreads();
    }
    const float inv = 1.0f / fmaxf(sqrtf(red[0]), 1e-12f);

    float o0, o1;
    if (n > 0) { o0 = v0 * inv; o1 = v1 * inv; }
    else       { o0 = p.x;      o1 = p.y;      }

    ushort2v b;
    b.x = f2bf(o0);
    b.y = f2bf(o1);
    *(ushort2v*)(pb + (size_t)c * 512 + t * 2) = b;
}

// ---------------------------------------------------------------------------
// Kernel 5: sim[N,C] = f[N,K] @ P[C,K]^T, bf16 in, fp32 out.
// 128x128 tile, BK=64, 16x16x32 bf16 MFMA, global_load_lds x16.
// NEW vs verified round-1 version (only this kernel changed):
//  (a) counted-vmcnt double-buffer: stage tile t+1 into buf^1 at loop top,
//      s_waitcnt vmcnt(8) (tile t's 8 gload_lds done, t+1's stay in flight),
//      raw s_barrier; end of iter: lgkmcnt(0) + s_barrier (no wave's in-flight
//      ds_read may race the next stage into this buffer). Never vmcnt(0)
//      in the main loop. LDS 2x32KB = 64 KB -> still 2 blocks/CU.
//  (b) bijective XCD swizzle: nwg=4096 %8==0; tile=(d&7)*(nwg/8)+d/8 puts the
//      8 column-tiles sharing an A-panel on the SAME XCD back-to-back
//      (per-XCD L2 working set ~2MB <= 4MB).
// ---------------------------------------------------------------------------
__global__ __launch_bounds__(256, 2) void k_gemm(
    const unsigned short* __restrict__ A, const unsigned short* __restrict__ B,
    float* __restrict__ out, int N, int C, int K)
{
    __shared__ unsigned short As[2][128 * 64];  // 2 x 16 KB
    __shared__ unsigned short Bs[2][128 * 64];  // 2 x 16 KB

    const int tid   = threadIdx.x;
    const int lane  = tid & 63;
    const int wv    = tid >> 6;
    const int waveM = wv >> 1, waveN = wv & 1;
    const int quad  = lane >> 4, l16 = lane & 15;

    // XCD-aware bijective swizzle of the flat block index (x-major dispatch)
    const int gx   = (int)gridDim.x;               // C/128 = 8
    const int nwg  = gx * (int)gridDim.y;          // 4096, divisible by 8
    const int d    = (int)(blockIdx.y * gridDim.x + blockIdx.x);
    const int tile = (d & 7) * (nwg >> 3) + (d >> 3);
    const size_t m0 = (size_t)(tile / gx) * 128;
    const size_t n0 = (size_t)(tile % gx) * 128;

    floatx4 zero = {0.0f, 0.0f, 0.0f, 0.0f};
    floatx4 acc[4][4];
#pragma unroll
    for (int i = 0; i < 4; ++i)
#pragma unroll
        for (int j = 0; j < 4; ++j) acc[i][j] = zero;

    const int arow = tid >> 3;        // 0..31 (row within a 32-row staging slab)
    const int kc8  = (tid & 7) * 8;   // k-chunk offset in elements

    const int NT = K >> 6;            // 8 K-tiles of BK=64

    // prologue: stage tile 0 into buffer 0 (8 gload_lds per thread)
#pragma unroll
    for (int t = 0; t < 4; ++t) {
        const unsigned short* ga = A + (m0 + (size_t)(t * 32 + arow)) * K + kc8;
        __builtin_amdgcn_global_load_lds(AS1C(ga), AS3(&As[0][(t * 256 + tid) * 8]), 16, 0, 0);
    }
#pragma unroll
    for (int t = 0; t < 4; ++t) {
        const unsigned short* gb = B + (n0 + (size_t)(t * 32 + arow)) * K + kc8;
        __builtin_amdgcn_global_load_lds(AS1C(gb), AS3(&Bs[0][(t * 256 + tid) * 8]), 16, 0, 0);
    }

    int cur = 0;
    for (int kt = 0; kt < NT - 1; ++kt) {
        const int k1 = (kt + 1) << 6;
        // stage next tile into buf^1 (this buffer's readers finished at the
        // end-of-previous-iteration barrier)
#pragma unroll
        for (int t = 0; t < 4; ++t) {
            const unsigned short* ga = A + (m0 + (size_t)(t * 32 + arow)) * K + (k1 + kc8);
            __builtin_amdgcn_global_load_lds(AS1C(ga), AS3(&As[cur ^ 1][(t * 256 + tid) * 8]), 16, 0, 0);
        }
#pragma unroll
        for (int t = 0; t < 4; ++t) {
            const unsigned short* gb = B + (n0 + (size_t)(t * 32 + arow)) * K + (k1 + kc8);
            __builtin_amdgcn_global_load_lds(AS1C(gb), AS3(&Bs[cur ^ 1][(t * 256 + tid) * 8]), 16, 0, 0);
        }
        // wait for tile kt's 8 loads only; tile kt+1's 8 remain in flight
        asm volatile("s_waitcnt vmcnt(8)" ::: "memory");
        __builtin_amdgcn_s_barrier();

        const unsigned short* __restrict__ Ab = &As[cur][0];
        const unsigned short* __restrict__ Bb = &Bs[cur][0];
#pragma unroll
        for (int s = 0; s < 2; ++s) {
            short8 af[4], bfr[4];
#pragma unroll
            for (int m = 0; m < 4; ++m)
                af[m] = *(const short8*)(Ab + (waveM * 64 + m * 16 + l16) * 64 + s * 32 + quad * 8);
#pragma unroll
            for (int n = 0; n < 4; ++n)
                bfr[n] = *(const short8*)(Bb + (waveN * 64 + n * 16 + l16) * 64 + s * 32 + quad * 8);
#pragma unroll
            for (int m = 0; m < 4; ++m)
#pragma unroll
                for (int n = 0; n < 4; ++n)
                    acc[m][n] = __builtin_amdgcn_mfma_f32_16x16x32_bf16(af[m], bfr[n], acc[m][n], 0, 0, 0);
        }
        // all this wave's ds_reads must complete before anyone re-stages cur
        asm volatile("s_waitcnt lgkmcnt(0)" ::: "memory");
        __builtin_amdgcn_s_barrier();
        cur ^= 1;
    }

    // final tile: drain everything, compute
    asm volatile("s_waitcnt vmcnt(0)" ::: "memory");
    __builtin_amdgcn_s_barrier();
    {
        const unsigned short* __restrict__ Ab = &As[cur][0];
        const unsigned short* __restrict__ Bb = &Bs[cur][0];
#pragma unroll
        for (int s = 0; s < 2; ++s) {
            short8 af[4], bfr[4];
#pragma unroll
            for (int m = 0; m < 4; ++m)
                af[m] = *(const short8*)(Ab + (waveM * 64 + m * 16 + l16) * 64 + s * 32 + quad * 8);
#pragma unroll
            for (int n = 0; n < 4; ++n)
                bfr[n] = *(const short8*)(Bb + (waveN * 64 + n * 16 + l16) * 64 + s * 32 + quad * 8);
#pragma unroll
            for (int m = 0; m < 4; ++m)
#pragma unroll
                for (int n = 0; n < 4; ++n)
                    acc[m][n] = __builtin_amdgcn_mfma_f32_16x16x32_bf16(af[m], bfr[n], acc[m][n], 0, 0, 0);
        }
    }

    // epilogue: C/D layout col=lane&15, row=(lane>>4)*4+reg
#pragma unroll
    for (int m = 0; m < 4; ++m) {
        const size_t r0 = m0 + (size_t)(waveM * 64 + m * 16 + quad * 4);
#pragma unroll
        for (int n = 0; n < 4; ++n) {
            const size_t c = n0 + (size_t)(waveN * 64 + n * 16 + l16);
#pragma unroll
            for (int r = 0; r < 4; ++r)
                out[(r0 + r) * (size_t)C + c] = acc[m][n][r];
        }
    }
}

// ---------------------------------------------------------------------------
extern "C" void kernel_launch(void* const* d_in, const int* in_sizes, int n_in,
                              void* d_out, int out_size, void* d_ws, size_t ws_size,
                              hipStream_t stream)
{
    const float* feats  = (const float*)d_in[0];
    const float* protos = (const float*)d_in[1];
    const int*   labels = (const int*)d_in[2];
    float* sim = (float*)d_out;

    const int D = 512;
    const int N = in_sizes[0] / D;   // 65536
    const int C = in_sizes[1] / D;   // 1024

    char* w = (char*)d_ws;
    unsigned short* fb = (unsigned short*)w;                 // N*D bf16 = 64 MB
    size_t off = (size_t)N * D * 2;
    unsigned short* pb = (unsigned short*)(w + off);         // C*D bf16 = 1 MB
    off += (size_t)C * D * 2;
    float* rnorm = (float*)(w + off);                        // N f32 = 256 KB
    off += (size_t)N * 4;
    int* idx = (int*)(w + off);                              // N i32 = 256 KB
    off += (size_t)N * 4;
    int* cnt = (int*)(w + off);                              // C i32
    off += (size_t)C * 4;
    int* offs = (int*)(w + off);                             // C i32
    off += (size_t)C * 4;
    int* cursor = (int*)(w + off);                           // C i32

    hipMemsetAsync(cnt, 0, (size_t)C * 4, stream);

    k_norm<<<dim3(N / 4), dim3(256), 0, stream>>>(feats, labels, fb, rnorm, cnt, N);
    k_scan<<<dim3(1), dim3(256), 0, stream>>>(cnt, offs, cursor, C);
    k_scatter_idx<<<dim3(N / 256), dim3(256), 0, stream>>>(labels, cursor, idx, N);
    k_segsum_update<<<dim3(C), dim3(256), 0, stream>>>(feats, rnorm, idx, offs, cnt, protos, pb);

    dim3 g(C / 128, N / 128);   // (8, 512)
    k_gemm<<<g, dim3(256), 0, stream>>>(fb, pb, sim, N, C, D);
}

// Round 4
// 461.658 us; speedup vs baseline: 1.0931x; 1.0931x over previous
//
#include <hip/hip_runtime.h>
#include <cstdint>
#include <cstddef>

typedef short short8 __attribute__((ext_vector_type(8)));
typedef float floatx4 __attribute__((ext_vector_type(4)));
typedef unsigned short ushort4v __attribute__((ext_vector_type(4)));
typedef unsigned short ushort2v __attribute__((ext_vector_type(2)));

#define AS1C(p) ((const __attribute__((address_space(1))) void*)(p))
#define AS3(p)  ((__attribute__((address_space(3))) void*)(p))

// round-to-nearest-even float -> bf16 bits
__device__ __forceinline__ unsigned short f2bf(float f) {
    union { float f; unsigned int u; } v; v.f = f;
    unsigned int u = v.u;
    unsigned int r = (u + 0x7fffu + ((u >> 16) & 1u)) >> 16;
    return (unsigned short)r;
}

__device__ __forceinline__ float wave_sum(float s) {
#pragma unroll
    for (int off = 32; off > 0; off >>= 1)
        s += __shfl_xor(s, off, 64);
    return s;
}

// ---------------------------------------------------------------------------
// Kernel 1: per-row l2norm of feats -> fb (bf16); store rnorm[i]; histogram
// labels with ONE int atomic per row. One wave per row of D=512.  (verified)
// ---------------------------------------------------------------------------
__global__ __launch_bounds__(256) void k_norm(
    const float* __restrict__ feats, const int* __restrict__ labels,
    unsigned short* __restrict__ fb, float* __restrict__ rnorm,
    int* __restrict__ cnt, int N)
{
    const int gw   = (int)((blockIdx.x * 256u + threadIdx.x) >> 6);
    const int lane = threadIdx.x & 63;
    if (gw >= N) return;

    const float* row = feats + (size_t)gw * 512;
    floatx4 x0 = *(const floatx4*)(row + lane * 4);
    floatx4 x1 = *(const floatx4*)(row + 256 + lane * 4);

    float s = x0.x * x0.x + x0.y * x0.y + x0.z * x0.z + x0.w * x0.w
            + x1.x * x1.x + x1.y * x1.y + x1.z * x1.z + x1.w * x1.w;
    s = wave_sum(s);
    const float inv = 1.0f / fmaxf(sqrtf(s), 1e-12f);

    floatx4 y0 = x0 * inv, y1 = x1 * inv;

    ushort4v b0, b1;
    b0.x = f2bf(y0.x); b0.y = f2bf(y0.y); b0.z = f2bf(y0.z); b0.w = f2bf(y0.w);
    b1.x = f2bf(y1.x); b1.y = f2bf(y1.y); b1.z = f2bf(y1.z); b1.w = f2bf(y1.w);
    *(ushort4v*)(fb + (size_t)gw * 512 + lane * 4)       = b0;
    *(ushort4v*)(fb + (size_t)gw * 512 + 256 + lane * 4) = b1;

    if (lane == 0) {
        rnorm[gw] = inv;
        atomicAdd(cnt + labels[gw], 1);
    }
}

// ---------------------------------------------------------------------------
// Kernel 2: exclusive prefix-sum of cnt[C] -> offs[C]; cursor = offs. (verified)
// ---------------------------------------------------------------------------
__global__ __launch_bounds__(256) void k_scan(
    const int* __restrict__ cnt, int* __restrict__ offs,
    int* __restrict__ cursor, int C)
{
    __shared__ int part[256];
    const int t = threadIdx.x;
    const int base = t * 4;
    int a0 = (base + 0 < C) ? cnt[base + 0] : 0;
    int a1 = (base + 1 < C) ? cnt[base + 1] : 0;
    int a2 = (base + 2 < C) ? cnt[base + 2] : 0;
    int a3 = (base + 3 < C) ? cnt[base + 3] : 0;
    const int s = a0 + a1 + a2 + a3;
    part[t] = s;
    __syncthreads();
#pragma unroll
    for (int off = 1; off < 256; off <<= 1) {
        int v = (t >= off) ? part[t - off] : 0;
        __syncthreads();
        part[t] += v;
        __syncthreads();
    }
    const int excl = part[t] - s;
    const int o0 = excl, o1 = o0 + a0, o2 = o1 + a1, o3 = o2 + a2;
    if (base + 0 < C) { offs[base + 0] = o0; cursor[base + 0] = o0; }
    if (base + 1 < C) { offs[base + 1] = o1; cursor[base + 1] = o1; }
    if (base + 2 < C) { offs[base + 2] = o2; cursor[base + 2] = o2; }
    if (base + 3 < C) { offs[base + 3] = o3; cursor[base + 3] = o3; }
}

// ---------------------------------------------------------------------------
// Kernel 3: build per-class row-index lists. (verified)
// ---------------------------------------------------------------------------
__global__ __launch_bounds__(256) void k_scatter_idx(
    const int* __restrict__ labels, int* __restrict__ cursor,
    int* __restrict__ idx, int N)
{
    const int i = (int)(blockIdx.x * 256u + threadIdx.x);
    if (i < N) {
        const int lab = labels[i];
        const int pos = atomicAdd(cursor + lab, 1);
        idx[pos] = i;
    }
}

// ---------------------------------------------------------------------------
// Kernel 4: per-class gather segment-sum + EMA + renorm; write pb (bf16). (verified)
// ---------------------------------------------------------------------------
__global__ __launch_bounds__(256) void k_segsum_update(
    const float* __restrict__ feats, const float* __restrict__ rnorm,
    const int* __restrict__ idx, const int* __restrict__ offs,
    const int* __restrict__ cnt, const float* __restrict__ protos,
    unsigned short* __restrict__ pb)
{
    const int c = blockIdx.x;
    const int t = threadIdx.x;
    const int n = cnt[c];
    const int o = offs[c];

    float a0 = 0.0f, a1 = 0.0f;
    int j = 0;
    for (; j + 4 <= n; j += 4) {
        const int r0 = idx[o + j + 0];
        const int r1 = idx[o + j + 1];
        const int r2 = idx[o + j + 2];
        const int r3 = idx[o + j + 3];
        const float2 v0 = *(const float2*)(feats + (size_t)r0 * 512 + t * 2);
        const float2 v1 = *(const float2*)(feats + (size_t)r1 * 512 + t * 2);
        const float2 v2 = *(const float2*)(feats + (size_t)r2 * 512 + t * 2);
        const float2 v3 = *(const float2*)(feats + (size_t)r3 * 512 + t * 2);
        const float s0 = rnorm[r0], s1 = rnorm[r1], s2 = rnorm[r2], s3 = rnorm[r3];
        a0 += v0.x * s0 + v1.x * s1 + v2.x * s2 + v3.x * s3;
        a1 += v0.y * s0 + v1.y * s1 + v2.y * s2 + v3.y * s3;
    }
    for (; j < n; ++j) {
        const int r = idx[o + j];
        const float2 v = *(const float2*)(feats + (size_t)r * 512 + t * 2);
        const float sc = rnorm[r];
        a0 += v.x * sc;
        a1 += v.y * sc;
    }

    const float2 p = *(const float2*)(protos + (size_t)c * 512 + t * 2);
    const float rc = 0.1f / fmaxf((float)n, 1.0f);
    const float v0 = 0.9f * p.x + rc * a0;
    const float v1 = 0.9f * p.y + rc * a1;

    __shared__ float red[256];
    red[t] = v0 * v0 + v1 * v1;
    __syncthreads();
#pragma unroll
    for (int off = 128; off > 0; off >>= 1) {
        if (t < off) red[t] += red[t + off];
        __syncthreads();
    }
    const float inv = 1.0f / fmaxf(sqrtf(red[0]), 1e-12f);

    float o0, o1;
    if (n > 0) { o0 = v0 * inv; o1 = v1 * inv; }
    else       { o0 = p.x;      o1 = p.y;      }

    ushort2v b;
    b.x = f2bf(o0);
    b.y = f2bf(o1);
    *(ushort2v*)(pb + (size_t)c * 512 + t * 2) = b;
}

// ---------------------------------------------------------------------------
// Kernel 5: sim[N,C] = f[N,512] @ P[C,512]^T, bf16 in, fp32 out.
// 256x256 tile, BK=64, 512 threads (8 waves: 2M x 4N, each 128x64 out).
// 8-phase schedule (T3+T4) + st_16x32 LDS swizzle (T2, pre-swizzled
// global_load_lds source) + setprio (T5).
//
// ROUND-4 FIX (tail race): at p3, vmcnt(6) assumes 7 STAGEs (14 loads) are
// outstanding — true only while the kt+2 prefetch stream exists (kt+2<NT).
// At kt==NT-2 only 8 loads are outstanding, so vmcnt(6) retired just 2 and
// the final tile's B-h1/A-h0/A-h1 were read while still in flight (absmax
// 0.119, concentrated in the last K-tile). Fix: vmcnt(0) when kt+2>=NT.
// Loop is fully unrolled, so the branch folds to the right immediate.
//
// Per-thread load ledger (2 loads per STAGE call):
//   prologue: 7 STAGEs, vmcnt(6) -> kt0's 4 units landed.
//   kt p0: stage Ah1(kt+1)->buf^1;  p1: Bh0(kt+2)->buf;  p2: Bh1(kt+2)->buf;
//   kt p3: stage Ah0(kt+2)->buf; vmcnt(6) retires exactly kt+1's 4 units.
// WAR safety: every slot overwrite is issued after the end-of-phase barrier
// that followed the last reader's lgkmcnt(0).
// ---------------------------------------------------------------------------
__global__ __launch_bounds__(512, 2) void k_gemm(
    const unsigned short* __restrict__ A, const unsigned short* __restrict__ B,
    float* __restrict__ out, int N, int C)
{
    constexpr int K  = 512;
    constexpr int NT = 8;                         // K / 64
    __shared__ unsigned short lds[2][4][128 * 64];  // 128 KB

    const int tid  = threadIdx.x;
    const int lane = tid & 63;
    const int wid  = tid >> 6;        // 0..7
    const int wm   = wid >> 2;        // 0..1  M-half
    const int wn   = wid & 3;         // 0..3  N-quarter
    const int quad = lane >> 4, l16 = lane & 15;
    // lane-constant swizzled (row&15, col&31) part of the ds_read offset
    const int lofs = l16 * 32 + ((quad * 8) ^ ((l16 >> 3) << 4));
    const int bRow = (wn & 1) * 4;    // B fragment row-group base

    const size_t m0 = (size_t)blockIdx.y * 256;
    const size_t n0 = (size_t)blockIdx.x * 256;

    // per-thread stage decode: granule G = i*512+tid holds logical
    // (row = (G>>7)*16 + r15, col = cg*32 + (cb ^ ((r15>>3)&1)<<1)*8)
    int pre[2], dstG[2];
#pragma unroll
    for (int i = 0; i < 2; ++i) {
        const int G   = i * 512 + tid;
        const int r15 = (G & 63) >> 2;
        const int row = (G >> 7) * 16 + r15;
        const int cbl = (G & 3) ^ (((r15 >> 3) & 1) << 1);
        const int col = ((G >> 6) & 1) * 32 + cbl * 8;
        pre[i]  = row * K + col;
        dstG[i] = G * 8;              // element offset in slot (16 B granules)
    }

#define STAGE(mat, rowbase, k0, slotp) do {                                        \
    _Pragma("unroll")                                                              \
    for (int i_ = 0; i_ < 2; ++i_)                                                 \
        __builtin_amdgcn_global_load_lds(                                          \
            AS1C((mat) + (size_t)(rowbase) * K + (k0) + pre[i_]),                  \
            AS3((slotp) + dstG[i_]), 16, 0, 0);                                    \
} while (0)

    floatx4 acc[8][4];
#pragma unroll
    for (int m = 0; m < 8; ++m)
#pragma unroll
        for (int n = 0; n < 4; ++n)
            acc[m][n] = (floatx4){0.0f, 0.0f, 0.0f, 0.0f};

    // prologue: 7 units (kt0 complete + Bh0,Bh1,Ah0 of kt1)
    STAGE(B, n0,       0,  &lds[0][2][0]);
    STAGE(B, n0 + 128, 0,  &lds[0][3][0]);
    STAGE(A, m0,       0,  &lds[0][0][0]);
    STAGE(A, m0 + 128, 0,  &lds[0][1][0]);
    STAGE(B, n0,       64, &lds[1][2][0]);
    STAGE(B, n0 + 128, 64, &lds[1][3][0]);
    STAGE(A, m0,       64, &lds[1][0][0]);
    asm volatile("s_waitcnt vmcnt(6)" ::: "memory");  // kt0's 4 units landed
    __builtin_amdgcn_s_barrier();

#pragma unroll
    for (int kt = 0; kt < NT; ++kt) {
        const int buf = kt & 1;
        const unsigned short* sA = &lds[buf][wm][0];
        const unsigned short* sB = &lds[buf][2 + (wn >> 1)][0];

        short8 bfr[4][2];   // B-frags, read @p0, live all 4 phases
        short8 ac[2][2];    // current quad A-frags
        short8 a3[2][2];    // quad3 A-frags, prefetched @p2

        // =============== phase 0: read B(all) + A-quad0; MFMA quad0 ========
#pragma unroll
        for (int n = 0; n < 4; ++n)
#pragma unroll
            for (int s = 0; s < 2; ++s)
                bfr[n][s] = *(const short8*)(sB + ((bRow + n) << 10) + (s << 9) + lofs);
#pragma unroll
        for (int ml = 0; ml < 2; ++ml)
#pragma unroll
            for (int s = 0; s < 2; ++s)
                ac[ml][s] = *(const short8*)(sA + ((0 + ml) << 10) + (s << 9) + lofs);
        if (kt + 1 < NT) STAGE(A, m0 + 128, (kt + 1) * 64, &lds[buf ^ 1][1][0]);
        __builtin_amdgcn_s_barrier();
        asm volatile("s_waitcnt lgkmcnt(0)" ::: "memory");
        __builtin_amdgcn_sched_barrier(0);
        __builtin_amdgcn_s_setprio(1);
#pragma unroll
        for (int ml = 0; ml < 2; ++ml)
#pragma unroll
            for (int n = 0; n < 4; ++n)
#pragma unroll
                for (int s = 0; s < 2; ++s)
                    acc[0 + ml][n] = __builtin_amdgcn_mfma_f32_16x16x32_bf16(ac[ml][s], bfr[n][s], acc[0 + ml][n], 0, 0, 0);
        __builtin_amdgcn_s_setprio(0);
        __builtin_amdgcn_sched_barrier(0);
        __builtin_amdgcn_s_barrier();

        // =============== phase 1: read A-quad1; MFMA quad1 =================
#pragma unroll
        for (int ml = 0; ml < 2; ++ml)
#pragma unroll
            for (int s = 0; s < 2; ++s)
                ac[ml][s] = *(const short8*)(sA + ((2 + ml) << 10) + (s << 9) + lofs);
        if (kt + 2 < NT) STAGE(B, n0, (kt + 2) * 64, &lds[buf][2][0]);
        __builtin_amdgcn_s_barrier();
        asm volatile("s_waitcnt lgkmcnt(0)" ::: "memory");
        __builtin_amdgcn_sched_barrier(0);
        __builtin_amdgcn_s_setprio(1);
#pragma unroll
        for (int ml = 0; ml < 2; ++ml)
#pragma unroll
            for (int n = 0; n < 4; ++n)
#pragma unroll
                for (int s = 0; s < 2; ++s)
                    acc[2 + ml][n] = __builtin_amdgcn_mfma_f32_16x16x32_bf16(ac[ml][s], bfr[n][s], acc[2 + ml][n], 0, 0, 0);
        __builtin_amdgcn_s_setprio(0);
        __builtin_amdgcn_sched_barrier(0);
        __builtin_amdgcn_s_barrier();

        // ======== phase 2: read A-quad2 + prefetch A-quad3; MFMA quad2 =====
#pragma unroll
        for (int ml = 0; ml < 2; ++ml)
#pragma unroll
            for (int s = 0; s < 2; ++s)
                ac[ml][s] = *(const short8*)(sA + ((4 + ml) << 10) + (s << 9) + lofs);
#pragma unroll
        for (int ml = 0; ml < 2; ++ml)
#pragma unroll
            for (int s = 0; s < 2; ++s)
                a3[ml][s] = *(const short8*)(sA + ((6 + ml) << 10) + (s << 9) + lofs);
        if (kt + 2 < NT) STAGE(B, n0 + 128, (kt + 2) * 64, &lds[buf][3][0]);
        __builtin_amdgcn_s_barrier();
        asm volatile("s_waitcnt lgkmcnt(0)" ::: "memory");
        __builtin_amdgcn_sched_barrier(0);
        __builtin_amdgcn_s_setprio(1);
#pragma unroll
        for (int ml = 0; ml < 2; ++ml)
#pragma unroll
            for (int n = 0; n < 4; ++n)
#pragma unroll
                for (int s = 0; s < 2; ++s)
                    acc[4 + ml][n] = __builtin_amdgcn_mfma_f32_16x16x32_bf16(ac[ml][s], bfr[n][s], acc[4 + ml][n], 0, 0, 0);
        __builtin_amdgcn_s_setprio(0);
        __builtin_amdgcn_sched_barrier(0);
        __builtin_amdgcn_s_barrier();

        // ====== phase 3: stage Ah0(kt+2); counted/drain vmcnt; MFMA quad3 ==
        if (kt + 2 < NT) {
            STAGE(A, m0, (kt + 2) * 64, &lds[buf][0][0]);
            // 7 STAGEs (14 loads) outstanding: retire oldest 8 = kt+1's units
            asm volatile("s_waitcnt vmcnt(6)" ::: "memory");
        } else {
            // tail (kt >= NT-2): no kt+2 stream; drain so the final tile's
            // Ah1 (staged at this kt's p0) is guaranteed landed before kt+1.
            asm volatile("s_waitcnt vmcnt(0)" ::: "memory");
        }
        __builtin_amdgcn_s_barrier();
        asm volatile("s_waitcnt lgkmcnt(0)" ::: "memory");
        __builtin_amdgcn_sched_barrier(0);
        __builtin_amdgcn_s_setprio(1);
#pragma unroll
        for (int ml = 0; ml < 2; ++ml)
#pragma unroll
            for (int n = 0; n < 4; ++n)
#pragma unroll
                for (int s = 0; s < 2; ++s)
                    acc[6 + ml][n] = __builtin_amdgcn_mfma_f32_16x16x32_bf16(a3[ml][s], bfr[n][s], acc[6 + ml][n], 0, 0, 0);
        __builtin_amdgcn_s_setprio(0);
        __builtin_amdgcn_sched_barrier(0);
        __builtin_amdgcn_s_barrier();
    }
#undef STAGE

    // epilogue: C/D layout col=lane&15, row=(lane>>4)*4+reg
#pragma unroll
    for (int m = 0; m < 8; ++m) {
        const size_t r0 = m0 + (size_t)(wm * 128 + m * 16 + quad * 4);
#pragma unroll
        for (int n = 0; n < 4; ++n) {
            const size_t c = n0 + (size_t)(wn * 64 + n * 16 + l16);
#pragma unroll
            for (int r = 0; r < 4; ++r)
                out[(r0 + r) * (size_t)C + c] = acc[m][n][r];
        }
    }
}

// ---------------------------------------------------------------------------
extern "C" void kernel_launch(void* const* d_in, const int* in_sizes, int n_in,
                              void* d_out, int out_size, void* d_ws, size_t ws_size,
                              hipStream_t stream)
{
    const float* feats  = (const float*)d_in[0];
    const float* protos = (const float*)d_in[1];
    const int*   labels = (const int*)d_in[2];
    float* sim = (float*)d_out;

    const int D = 512;
    const int N = in_sizes[0] / D;   // 65536
    const int C = in_sizes[1] / D;   // 1024

    char* w = (char*)d_ws;
    unsigned short* fb = (unsigned short*)w;                 // N*D bf16 = 64 MB
    size_t off = (size_t)N * D * 2;
    unsigned short* pb = (unsigned short*)(w + off);         // C*D bf16 = 1 MB
    off += (size_t)C * D * 2;
    float* rnorm = (float*)(w + off);                        // N f32 = 256 KB
    off += (size_t)N * 4;
    int* idx = (int*)(w + off);                              // N i32 = 256 KB
    off += (size_t)N * 4;
    int* cnt = (int*)(w + off);                              // C i32
    off += (size_t)C * 4;
    int* offs = (int*)(w + off);                             // C i32
    off += (size_t)C * 4;
    int* cursor = (int*)(w + off);                           // C i32

    hipMemsetAsync(cnt, 0, (size_t)C * 4, stream);

    k_norm<<<dim3(N / 4), dim3(256), 0, stream>>>(feats, labels, fb, rnorm, cnt, N);
    k_scan<<<dim3(1), dim3(256), 0, stream>>>(cnt, offs, cursor, C);
    k_scatter_idx<<<dim3(N / 256), dim3(256), 0, stream>>>(labels, cursor, idx, N);
    k_segsum_update<<<dim3(C), dim3(256), 0, stream>>>(feats, rnorm, idx, offs, cnt, protos, pb);

    dim3 g(C / 256, N / 256);   // (4, 256)
    k_gemm<<<g, dim3(512), 0, stream>>>(fb, pb, sim, N, C);
}

// Round 5
// 433.232 us; speedup vs baseline: 1.1648x; 1.0656x over previous
//
#include <hip/hip_runtime.h>
#include <cstdint>
#include <cstddef>

typedef short short8 __attribute__((ext_vector_type(8)));
typedef float floatx4 __attribute__((ext_vector_type(4)));
typedef unsigned short ushort4v __attribute__((ext_vector_type(4)));
typedef unsigned short ushort2v __attribute__((ext_vector_type(2)));

#define AS1C(p) ((const __attribute__((address_space(1))) void*)(p))
#define AS3(p)  ((__attribute__((address_space(3))) void*)(p))

// round-to-nearest-even float -> bf16 bits
__device__ __forceinline__ unsigned short f2bf(float f) {
    union { float f; unsigned int u; } v; v.f = f;
    unsigned int u = v.u;
    unsigned int r = (u + 0x7fffu + ((u >> 16) & 1u)) >> 16;
    return (unsigned short)r;
}

__device__ __forceinline__ float bf2f(unsigned short b) {
    union { unsigned int u; float f; } v;
    v.u = (unsigned int)b << 16;
    return v.f;
}

__device__ __forceinline__ float wave_sum(float s) {
#pragma unroll
    for (int off = 32; off > 0; off >>= 1)
        s += __shfl_xor(s, off, 64);
    return s;
}

// ---------------------------------------------------------------------------
// Kernel 1: per-row l2norm of feats -> fb (bf16); slot-assign directly:
// pos = atomicAdd(cnt[lab]) gives each row a unique slot in idx2[lab][512].
// Replaces the old k_norm + k_scan + k_scatter_idx triple (removes the
// 1-block scan serialization bubble and 2 launch gaps).
// One wave (64 lanes) per row of D=512.
// ---------------------------------------------------------------------------
__global__ __launch_bounds__(256) void k_norm(
    const float* __restrict__ feats, const int* __restrict__ labels,
    unsigned short* __restrict__ fb, int* __restrict__ cnt,
    int* __restrict__ idx2, int N)
{
    const int gw   = (int)((blockIdx.x * 256u + threadIdx.x) >> 6);
    const int lane = threadIdx.x & 63;
    if (gw >= N) return;

    const float* row = feats + (size_t)gw * 512;
    floatx4 x0 = *(const floatx4*)(row + lane * 4);
    floatx4 x1 = *(const floatx4*)(row + 256 + lane * 4);

    float s = x0.x * x0.x + x0.y * x0.y + x0.z * x0.z + x0.w * x0.w
            + x1.x * x1.x + x1.y * x1.y + x1.z * x1.z + x1.w * x1.w;
    s = wave_sum(s);
    const float inv = 1.0f / fmaxf(sqrtf(s), 1e-12f);

    floatx4 y0 = x0 * inv, y1 = x1 * inv;

    ushort4v b0, b1;
    b0.x = f2bf(y0.x); b0.y = f2bf(y0.y); b0.z = f2bf(y0.z); b0.w = f2bf(y0.w);
    b1.x = f2bf(y1.x); b1.y = f2bf(y1.y); b1.z = f2bf(y1.z); b1.w = f2bf(y1.w);
    *(ushort4v*)(fb + (size_t)gw * 512 + lane * 4)       = b0;
    *(ushort4v*)(fb + (size_t)gw * 512 + 256 + lane * 4) = b1;

    if (lane == 0) {
        const int lab = labels[gw];
        const int pos = atomicAdd(cnt + lab, 1);
        // Poisson(64) max ~110 << 512; clamp guards memory regardless.
        if (pos < 512) idx2[lab * 512 + pos] = gw;
    }
}

// ---------------------------------------------------------------------------
// Kernel 2: per-class gather segment-mean FROM fb (bf16, already normalized;
// saves the 128 MB fp32 feats re-read) + EMA + renorm; write pb (bf16).
// One block per class; thread t owns columns 2t, 2t+1. 4 rows in flight.
// ---------------------------------------------------------------------------
__global__ __launch_bounds__(256) void k_segsum_update(
    const unsigned short* __restrict__ fb, const int* __restrict__ idx2,
    const int* __restrict__ cnt, const float* __restrict__ protos,
    unsigned short* __restrict__ pb)
{
    const int c = blockIdx.x;
    const int t = threadIdx.x;
    const int n  = cnt[c];
    const int nr = n < 512 ? n : 512;
    const int* lst = idx2 + c * 512;

    float a0 = 0.0f, a1 = 0.0f;
    int j = 0;
    for (; j + 4 <= nr; j += 4) {
        const int4 r = *(const int4*)(lst + j);
        const ushort2v v0 = *(const ushort2v*)(fb + (size_t)r.x * 512 + t * 2);
        const ushort2v v1 = *(const ushort2v*)(fb + (size_t)r.y * 512 + t * 2);
        const ushort2v v2 = *(const ushort2v*)(fb + (size_t)r.z * 512 + t * 2);
        const ushort2v v3 = *(const ushort2v*)(fb + (size_t)r.w * 512 + t * 2);
        a0 += bf2f(v0.x) + bf2f(v1.x) + bf2f(v2.x) + bf2f(v3.x);
        a1 += bf2f(v0.y) + bf2f(v1.y) + bf2f(v2.y) + bf2f(v3.y);
    }
    for (; j < nr; ++j) {
        const int r = lst[j];
        const ushort2v v = *(const ushort2v*)(fb + (size_t)r * 512 + t * 2);
        a0 += bf2f(v.x);
        a1 += bf2f(v.y);
    }

    const float2 p = *(const float2*)(protos + (size_t)c * 512 + t * 2);
    const float rc = 0.1f / fmaxf((float)n, 1.0f);
    const float v0 = 0.9f * p.x + rc * a0;
    const float v1 = 0.9f * p.y + rc * a1;

    __shared__ float red[256];
    red[t] = v0 * v0 + v1 * v1;
    __syncthreads();
#pragma unroll
    for (int off = 128; off > 0; off >>= 1) {
        if (t < off) red[t] += red[t + off];
        __syncthreads();
    }
    const float inv = 1.0f / fmaxf(sqrtf(red[0]), 1e-12f);

    float o0, o1;
    if (n > 0) { o0 = v0 * inv; o1 = v1 * inv; }
    else       { o0 = p.x;      o1 = p.y;      }

    ushort2v b;
    b.x = f2bf(o0);
    b.y = f2bf(o1);
    *(ushort2v*)(pb + (size_t)c * 512 + t * 2) = b;
}

// ---------------------------------------------------------------------------
// Kernel 3: sim[N,C] = f[N,512] @ P[C,512]^T, bf16 in, fp32 out.
// 256x256 tile, BK=64, 512 threads (8 waves: 2M x 4N, each 128x64 out).
// 8-phase schedule (T3+T4) + st_16x32 LDS swizzle (T2, pre-swizzled
// global_load_lds source) + setprio (T5).  UNCHANGED from verified round-4.
//
// Per-thread load ledger (2 loads per STAGE call):
//   prologue: 7 STAGEs, vmcnt(6) -> kt0's 4 units landed.
//   kt p0: stage Ah1(kt+1)->buf^1;  p1: Bh0(kt+2)->buf;  p2: Bh1(kt+2)->buf;
//   kt p3: stage Ah0(kt+2)->buf; vmcnt(6) retires exactly kt+1's 4 units.
//   tail (kt+2>=NT): vmcnt(0) drain (vmcnt(6) would retire too few).
// WAR safety: every slot overwrite is issued after the end-of-phase barrier
// that followed the last reader's lgkmcnt(0).
// ---------------------------------------------------------------------------
__global__ __launch_bounds__(512, 2) void k_gemm(
    const unsigned short* __restrict__ A, const unsigned short* __restrict__ B,
    float* __restrict__ out, int N, int C)
{
    constexpr int K  = 512;
    constexpr int NT = 8;                         // K / 64
    __shared__ unsigned short lds[2][4][128 * 64];  // 128 KB

    const int tid  = threadIdx.x;
    const int lane = tid & 63;
    const int wid  = tid >> 6;        // 0..7
    const int wm   = wid >> 2;        // 0..1  M-half
    const int wn   = wid & 3;         // 0..3  N-quarter
    const int quad = lane >> 4, l16 = lane & 15;
    // lane-constant swizzled (row&15, col&31) part of the ds_read offset
    const int lofs = l16 * 32 + ((quad * 8) ^ ((l16 >> 3) << 4));
    const int bRow = (wn & 1) * 4;    // B fragment row-group base

    const size_t m0 = (size_t)blockIdx.y * 256;
    const size_t n0 = (size_t)blockIdx.x * 256;

    // per-thread stage decode: granule G = i*512+tid holds logical
    // (row = (G>>7)*16 + r15, col = cg*32 + (cb ^ ((r15>>3)&1)<<1)*8)
    int pre[2], dstG[2];
#pragma unroll
    for (int i = 0; i < 2; ++i) {
        const int G   = i * 512 + tid;
        const int r15 = (G & 63) >> 2;
        const int row = (G >> 7) * 16 + r15;
        const int cbl = (G & 3) ^ (((r15 >> 3) & 1) << 1);
        const int col = ((G >> 6) & 1) * 32 + cbl * 8;
        pre[i]  = row * K + col;
        dstG[i] = G * 8;              // element offset in slot (16 B granules)
    }

#define STAGE(mat, rowbase, k0, slotp) do {                                        \
    _Pragma("unroll")                                                              \
    for (int i_ = 0; i_ < 2; ++i_)                                                 \
        __builtin_amdgcn_global_load_lds(                                          \
            AS1C((mat) + (size_t)(rowbase) * K + (k0) + pre[i_]),                  \
            AS3((slotp) + dstG[i_]), 16, 0, 0);                                    \
} while (0)

    floatx4 acc[8][4];
#pragma unroll
    for (int m = 0; m < 8; ++m)
#pragma unroll
        for (int n = 0; n < 4; ++n)
            acc[m][n] = (floatx4){0.0f, 0.0f, 0.0f, 0.0f};

    // prologue: 7 units (kt0 complete + Bh0,Bh1,Ah0 of kt1)
    STAGE(B, n0,       0,  &lds[0][2][0]);
    STAGE(B, n0 + 128, 0,  &lds[0][3][0]);
    STAGE(A, m0,       0,  &lds[0][0][0]);
    STAGE(A, m0 + 128, 0,  &lds[0][1][0]);
    STAGE(B, n0,       64, &lds[1][2][0]);
    STAGE(B, n0 + 128, 64, &lds[1][3][0]);
    STAGE(A, m0,       64, &lds[1][0][0]);
    asm volatile("s_waitcnt vmcnt(6)" ::: "memory");  // kt0's 4 units landed
    __builtin_amdgcn_s_barrier();

#pragma unroll
    for (int kt = 0; kt < NT; ++kt) {
        const int buf = kt & 1;
        const unsigned short* sA = &lds[buf][wm][0];
        const unsigned short* sB = &lds[buf][2 + (wn >> 1)][0];

        short8 bfr[4][2];   // B-frags, read @p0, live all 4 phases
        short8 ac[2][2];    // current quad A-frags
        short8 a3[2][2];    // quad3 A-frags, prefetched @p2

        // =============== phase 0: read B(all) + A-quad0; MFMA quad0 ========
#pragma unroll
        for (int n = 0; n < 4; ++n)
#pragma unroll
            for (int s = 0; s < 2; ++s)
                bfr[n][s] = *(const short8*)(sB + ((bRow + n) << 10) + (s << 9) + lofs);
#pragma unroll
        for (int ml = 0; ml < 2; ++ml)
#pragma unroll
            for (int s = 0; s < 2; ++s)
                ac[ml][s] = *(const short8*)(sA + ((0 + ml) << 10) + (s << 9) + lofs);
        if (kt + 1 < NT) STAGE(A, m0 + 128, (kt + 1) * 64, &lds[buf ^ 1][1][0]);
        __builtin_amdgcn_s_barrier();
        asm volatile("s_waitcnt lgkmcnt(0)" ::: "memory");
        __builtin_amdgcn_sched_barrier(0);
        __builtin_amdgcn_s_setprio(1);
#pragma unroll
        for (int ml = 0; ml < 2; ++ml)
#pragma unroll
            for (int n = 0; n < 4; ++n)
#pragma unroll
                for (int s = 0; s < 2; ++s)
                    acc[0 + ml][n] = __builtin_amdgcn_mfma_f32_16x16x32_bf16(ac[ml][s], bfr[n][s], acc[0 + ml][n], 0, 0, 0);
        __builtin_amdgcn_s_setprio(0);
        __builtin_amdgcn_sched_barrier(0);
        __builtin_amdgcn_s_barrier();

        // =============== phase 1: read A-quad1; MFMA quad1 =================
#pragma unroll
        for (int ml = 0; ml < 2; ++ml)
#pragma unroll
            for (int s = 0; s < 2; ++s)
                ac[ml][s] = *(const short8*)(sA + ((2 + ml) << 10) + (s << 9) + lofs);
        if (kt + 2 < NT) STAGE(B, n0, (kt + 2) * 64, &lds[buf][2][0]);
        __builtin_amdgcn_s_barrier();
        asm volatile("s_waitcnt lgkmcnt(0)" ::: "memory");
        __builtin_amdgcn_sched_barrier(0);
        __builtin_amdgcn_s_setprio(1);
#pragma unroll
        for (int ml = 0; ml < 2; ++ml)
#pragma unroll
            for (int n = 0; n < 4; ++n)
#pragma unroll
                for (int s = 0; s < 2; ++s)
                    acc[2 + ml][n] = __builtin_amdgcn_mfma_f32_16x16x32_bf16(ac[ml][s], bfr[n][s], acc[2 + ml][n], 0, 0, 0);
        __builtin_amdgcn_s_setprio(0);
        __builtin_amdgcn_sched_barrier(0);
        __builtin_amdgcn_s_barrier();

        // ======== phase 2: read A-quad2 + prefetch A-quad3; MFMA quad2 =====
#pragma unroll
        for (int ml = 0; ml < 2; ++ml)
#pragma unroll
            for (int s = 0; s < 2; ++s)
                ac[ml][s] = *(const short8*)(sA + ((4 + ml) << 10) + (s << 9) + lofs);
#pragma unroll
        for (int ml = 0; ml < 2; ++ml)
#pragma unroll
            for (int s = 0; s < 2; ++s)
                a3[ml][s] = *(const short8*)(sA + ((6 + ml) << 10) + (s << 9) + lofs);
        if (kt + 2 < NT) STAGE(B, n0 + 128, (kt + 2) * 64, &lds[buf][3][0]);
        __builtin_amdgcn_s_barrier();
        asm volatile("s_waitcnt lgkmcnt(0)" ::: "memory");
        __builtin_amdgcn_sched_barrier(0);
        __builtin_amdgcn_s_setprio(1);
#pragma unroll
        for (int ml = 0; ml < 2; ++ml)
#pragma unroll
            for (int n = 0; n < 4; ++n)
#pragma unroll
                for (int s = 0; s < 2; ++s)
                    acc[4 + ml][n] = __builtin_amdgcn_mfma_f32_16x16x32_bf16(ac[ml][s], bfr[n][s], acc[4 + ml][n], 0, 0, 0);
        __builtin_amdgcn_s_setprio(0);
        __builtin_amdgcn_sched_barrier(0);
        __builtin_amdgcn_s_barrier();

        // ====== phase 3: stage Ah0(kt+2); counted/drain vmcnt; MFMA quad3 ==
        if (kt + 2 < NT) {
            STAGE(A, m0, (kt + 2) * 64, &lds[buf][0][0]);
            // 7 STAGEs (14 loads) outstanding: retire oldest 8 = kt+1's units
            asm volatile("s_waitcnt vmcnt(6)" ::: "memory");
        } else {
            // tail (kt >= NT-2): no kt+2 stream; drain so the final tile's
            // Ah1 (staged at this kt's p0) is guaranteed landed before kt+1.
            asm volatile("s_waitcnt vmcnt(0)" ::: "memory");
        }
        __builtin_amdgcn_s_barrier();
        asm volatile("s_waitcnt lgkmcnt(0)" ::: "memory");
        __builtin_amdgcn_sched_barrier(0);
        __builtin_amdgcn_s_setprio(1);
#pragma unroll
        for (int ml = 0; ml < 2; ++ml)
#pragma unroll
            for (int n = 0; n < 4; ++n)
#pragma unroll
                for (int s = 0; s < 2; ++s)
                    acc[6 + ml][n] = __builtin_amdgcn_mfma_f32_16x16x32_bf16(a3[ml][s], bfr[n][s], acc[6 + ml][n], 0, 0, 0);
        __builtin_amdgcn_s_setprio(0);
        __builtin_amdgcn_sched_barrier(0);
        __builtin_amdgcn_s_barrier();
    }
#undef STAGE

    // epilogue: C/D layout col=lane&15, row=(lane>>4)*4+reg
#pragma unroll
    for (int m = 0; m < 8; ++m) {
        const size_t r0 = m0 + (size_t)(wm * 128 + m * 16 + quad * 4);
#pragma unroll
        for (int n = 0; n < 4; ++n) {
            const size_t c = n0 + (size_t)(wn * 64 + n * 16 + l16);
#pragma unroll
            for (int r = 0; r < 4; ++r)
                out[(r0 + r) * (size_t)C + c] = acc[m][n][r];
        }
    }
}

// ---------------------------------------------------------------------------
extern "C" void kernel_launch(void* const* d_in, const int* in_sizes, int n_in,
                              void* d_out, int out_size, void* d_ws, size_t ws_size,
                              hipStream_t stream)
{
    const float* feats  = (const float*)d_in[0];
    const float* protos = (const float*)d_in[1];
    const int*   labels = (const int*)d_in[2];
    float* sim = (float*)d_out;

    const int D = 512;
    const int N = in_sizes[0] / D;   // 65536
    const int C = in_sizes[1] / D;   // 1024

    char* w = (char*)d_ws;
    unsigned short* fb = (unsigned short*)w;                 // N*D bf16 = 64 MB
    size_t off = (size_t)N * D * 2;
    unsigned short* pb = (unsigned short*)(w + off);         // C*D bf16 = 1 MB
    off += (size_t)C * D * 2;
    int* idx2 = (int*)(w + off);                             // C*512 i32 = 2 MB
    off += (size_t)C * 512 * 4;
    int* cnt = (int*)(w + off);                              // C i32

    hipMemsetAsync(cnt, 0, (size_t)C * 4, stream);

    k_norm<<<dim3(N / 4), dim3(256), 0, stream>>>(feats, labels, fb, cnt, idx2, N);
    k_segsum_update<<<dim3(C), dim3(256), 0, stream>>>(fb, idx2, cnt, protos, pb);

    dim3 g(C / 256, N / 256);   // (4, 256)
    k_gemm<<<g, dim3(512), 0, stream>>>(fb, pb, sim, N, C);
}